// Round 9
// baseline (186.361 us; speedup 1.0000x reference)
//
#include <hip/hip_runtime.h>

// DisMaxLossFirstPart: logits = -|ds|*(dist + mean_c(dist)) / temp
// dist[b,c] = sqrt(max(1 - <fn_b, pn_c>, 0)), fn/pn L2-normalized rows.
// B=32768, C=1000, F=256. fp32 in/out; bf16 MFMA internally.
//
// Round 11: R10 base (global_load_lds ring, counted vmcnt, wave-private,
// (256,2)) + MFMA dependency-split. R10 == R2-kernel time proved staging
// latency is covered; remaining stall is the dependent-MFMA chain (2
// interleaved chains of 8, dep distance 2 instr ~10cy < result latency) at
// only 2 waves/SIMD. Split each acc into two K-half partials -> 4 indep
// chains of 4, dep distance 4 instr (~20cy) -> MFMA pipe fed by one wave.
// Cost: +8 acc VGPRs, 8 fp32 adds/tile (reassociation noise ~1e-6).

typedef __attribute__((ext_vector_type(8))) short short8;
typedef __attribute__((ext_vector_type(4))) float f32x4;
typedef __fp16 h2 __attribute__((ext_vector_type(2)));   // matches cvt_pkrtz return

union U16 { uint4 u4; short8 s8; };

static __device__ __forceinline__ unsigned short f2bf(float x){
  union { float f; unsigned u; } v; v.f = x;
  unsigned r = v.u + 0x7fffu + ((v.u >> 16) & 1u);   // RNE
  return (unsigned short)(r >> 16);
}

#define CPAD 1024          // prototype rows padded to 1024

// Normalize prototypes [C x 256] fp32 -> bf16 in fragment-ready permuted
// layout: 16B chunk index (t*8 + s)*64 + quad*16 + l16 holds
// pn[t*16 + l16][quad*8 + s*32 .. +8]. Rows >= C written as zeros.
__global__ void norm_protos_kernel(const float* __restrict__ src,
                                   unsigned short* __restrict__ dst, int C)
{
  const int wave = threadIdx.x >> 6;
  const int lane = threadIdx.x & 63;
  const int row  = blockIdx.x * 4 + wave;     // 0..1023
  const int t    = row >> 4;
  const int l16  = row & 15;
  const int s    = lane >> 3;                 // element e=4l: s = e>>5
  const int quad = (lane >> 1) & 3;           // quad = (e>>3)&3
  const int j    = (lane & 1) * 4;            // j = e&7 in {0,4}

  ushort4 o = {0, 0, 0, 0};
  if (row < C){
    const float4 v = *(const float4*)(src + row * 256 + lane * 4);
    float ss = v.x*v.x + v.y*v.y + v.z*v.z + v.w*v.w;
    #pragma unroll
    for (int off = 32; off; off >>= 1) ss += __shfl_xor(ss, off);
    const float inv = 1.0f / fmaxf(sqrtf(ss), 1e-12f);
    o.x = f2bf(v.x * inv); o.y = f2bf(v.y * inv);
    o.z = f2bf(v.z * inv); o.w = f2bf(v.w * inv);
  }
  *(ushort4*)(dst + ((size_t)((t*8 + s)*64 + quad*16 + l16))*8 + j) = o;
}

// counted waits; sched_barrier stops the compiler from reordering dependent
// ds_reads above the wait
#define VMWAIT8 do{ asm volatile("s_waitcnt vmcnt(8)" ::: "memory"); \
                    __builtin_amdgcn_sched_barrier(0); }while(0)
#define VMWAIT0 do{ asm volatile("s_waitcnt vmcnt(0)" ::: "memory"); \
                    __builtin_amdgcn_sched_barrier(0); }while(0)

__global__ __launch_bounds__(256, 2)
void fused_kernel(const float* __restrict__ feats,
                  const unsigned short* __restrict__ pnw,
                  const float* __restrict__ ds,
                  const float* __restrict__ temp,
                  float* __restrict__ out, int C)
{
  __shared__ uint4 pring[4][2][512];        // [wave][slot][8KB tile] = 64 KB
  __shared__ float wsum[2][16][4];          // [row-group][l16][wave]

  const int tid  = threadIdx.x;
  const int wave = tid >> 6;
  const int lane = tid & 63;
  const int quad = lane >> 4;
  const int l16  = lane & 15;
  const long rowbase = (long)blockIdx.x * 32;

  // ---- Phase 0: B-fragments (features) for 2 row-groups, norm fused ----
  short8 ffrag[2][8];
  #pragma unroll
  for (int rg = 0; rg < 2; ++rg){
    const float* rp = feats + (rowbase + rg*16 + l16) * 256 + quad*8;
    float4 va[8], vb[8];
    float ss = 0.f;
    #pragma unroll
    for (int s = 0; s < 8; ++s){
      va[s] = *(const float4*)(rp + s*32);
      vb[s] = *(const float4*)(rp + s*32 + 4);
      ss += va[s].x*va[s].x + va[s].y*va[s].y + va[s].z*va[s].z + va[s].w*va[s].w;
      ss += vb[s].x*vb[s].x + vb[s].y*vb[s].y + vb[s].z*vb[s].z + vb[s].w*vb[s].w;
    }
    ss += __shfl_xor(ss, 16);
    ss += __shfl_xor(ss, 32);
    const float inv = __builtin_amdgcn_rcpf(__builtin_amdgcn_sqrtf(fmaxf(ss, 1e-24f)));
    #pragma unroll
    for (int s = 0; s < 8; ++s){
      U16 u;
      u.u4.x = (unsigned)f2bf(va[s].x*inv) | ((unsigned)f2bf(va[s].y*inv) << 16);
      u.u4.y = (unsigned)f2bf(va[s].z*inv) | ((unsigned)f2bf(va[s].w*inv) << 16);
      u.u4.z = (unsigned)f2bf(vb[s].x*inv) | ((unsigned)f2bf(vb[s].y*inv) << 16);
      u.u4.w = (unsigned)f2bf(vb[s].z*inv) | ((unsigned)f2bf(vb[s].w*inv) << 16);
      ffrag[rg][s] = u.s8;
    }
  }

  // per-lane global src: (wave*16 + wt)*512 + s*64 + lane  (uint4 units)
  const uint4* tpg = (const uint4*)pnw + (size_t)(wave*16)*512 + lane;

  // stage tile wt into slot: 8x global_load_lds width=16, wave-linear dest
  #define STAGE(wt, slot) do{                                               \
      const uint4* g_ = tpg + (size_t)(wt)*512;                             \
      _Pragma("unroll")                                                     \
      for (int s_ = 0; s_ < 8; ++s_)                                        \
        __builtin_amdgcn_global_load_lds(                                   \
          (const __attribute__((address_space(1))) void*)(g_ + s_*64),      \
          (__attribute__((address_space(3))) void*)(&pring[wave][slot][s_*64]), \
          16, 0, 0);                                                        \
    }while(0)

  // prologue: two tiles in flight (vmcnt = 16)
  __builtin_amdgcn_sched_barrier(0);
  STAGE(0, 0);
  STAGE(1, 1);

  h2 dd0[16][2];     // rg0 dist strip, fp16-packed (32 VGPRs)
  h2 dd1[16][2];     // rg1
  float rsum0 = 0.f, rsum1 = 0.f;

  #pragma unroll
  for (int wt = 0; wt < 16; ++wt){
    // wait for tile wt (8 outstanding = next tile's loads still in flight)
    if (wt < 15) { VMWAIT8; } else { VMWAIT0; }

    const uint4* l = &pring[wave][wt & 1][0];
    short8 pfrag[8];
    #pragma unroll
    for (int s = 0; s < 8; ++s){ U16 u; u.u4 = l[s*64 + lane]; pfrag[s] = u.s8; }

    // 4 independent MFMA chains of length 4 (dep distance 4 instructions)
    f32x4 ac00 = (f32x4){0.f, 0.f, 0.f, 0.f};   // rg0, K-half 0
    f32x4 ac01 = (f32x4){0.f, 0.f, 0.f, 0.f};   // rg0, K-half 1
    f32x4 ac10 = (f32x4){0.f, 0.f, 0.f, 0.f};   // rg1, K-half 0
    f32x4 ac11 = (f32x4){0.f, 0.f, 0.f, 0.f};   // rg1, K-half 1
    __builtin_amdgcn_s_setprio(1);
    #pragma unroll
    for (int s = 0; s < 4; ++s){
      ac00 = __builtin_amdgcn_mfma_f32_16x16x32_bf16(pfrag[s],   ffrag[0][s],   ac00, 0, 0, 0);
      ac10 = __builtin_amdgcn_mfma_f32_16x16x32_bf16(pfrag[s],   ffrag[1][s],   ac10, 0, 0, 0);
      ac01 = __builtin_amdgcn_mfma_f32_16x16x32_bf16(pfrag[s+4], ffrag[0][s+4], ac01, 0, 0, 0);
      ac11 = __builtin_amdgcn_mfma_f32_16x16x32_bf16(pfrag[s+4], ffrag[1][s+4], ac11, 0, 0, 0);
    }
    __builtin_amdgcn_s_setprio(0);
    const f32x4 acc0 = ac00 + ac01;
    const f32x4 acc1 = ac10 + ac11;

    // refill the slot just consumed (ds_reads above already waited to regs)
    if (wt + 2 < 16){
      __builtin_amdgcn_sched_barrier(0);
      STAGE(wt + 2, wt & 1);
    }

    float a0 = __builtin_amdgcn_sqrtf(fmaxf(1.0f - acc0[0], 0.0f));
    float a1 = __builtin_amdgcn_sqrtf(fmaxf(1.0f - acc0[1], 0.0f));
    float a2 = __builtin_amdgcn_sqrtf(fmaxf(1.0f - acc0[2], 0.0f));
    float a3 = __builtin_amdgcn_sqrtf(fmaxf(1.0f - acc0[3], 0.0f));
    float b0 = __builtin_amdgcn_sqrtf(fmaxf(1.0f - acc1[0], 0.0f));
    float b1 = __builtin_amdgcn_sqrtf(fmaxf(1.0f - acc1[1], 0.0f));
    float b2 = __builtin_amdgcn_sqrtf(fmaxf(1.0f - acc1[2], 0.0f));
    float b3 = __builtin_amdgcn_sqrtf(fmaxf(1.0f - acc1[3], 0.0f));

    const int cls = wave*256 + wt*16 + quad*4;   // C%4==0: all-or-nothing
    rsum0 += (cls < C) ? (a0 + a1 + a2 + a3) : 0.0f;
    rsum1 += (cls < C) ? (b0 + b1 + b2 + b3) : 0.0f;

    dd0[wt][0] = __builtin_amdgcn_cvt_pkrtz(a0, a1);
    dd0[wt][1] = __builtin_amdgcn_cvt_pkrtz(a2, a3);
    dd1[wt][0] = __builtin_amdgcn_cvt_pkrtz(b0, b1);
    dd1[wt][1] = __builtin_amdgcn_cvt_pkrtz(b2, b3);
  }
  #undef STAGE

  // ---- Row means: reduce over quads, exchange across waves ----
  rsum0 += __shfl_xor(rsum0, 16);
  rsum0 += __shfl_xor(rsum0, 32);
  rsum1 += __shfl_xor(rsum1, 16);
  rsum1 += __shfl_xor(rsum1, 32);
  if (quad == 0){
    wsum[0][l16][wave] = rsum0;
    wsum[1][l16][wave] = rsum1;
  }
  __syncthreads();

  const float nscale = -fabsf(ds[0]) / temp[0];
  const float4 w0 = *(const float4*)&wsum[0][l16][0];
  const float4 w1 = *(const float4*)&wsum[1][l16][0];
  const float bias0 = nscale * ((w0.x + w0.y + w0.z + w0.w) / (float)C);
  const float bias1 = nscale * ((w1.x + w1.y + w1.z + w1.w) / (float)C);

  // ---- Epilogue: coalesced float4 stores, 2 rows per lane ----
  float* orow0 = out + (rowbase + l16) * (size_t)C;
  float* orow1 = out + (rowbase + 16 + l16) * (size_t)C;
  #pragma unroll
  for (int wt = 0; wt < 16; ++wt){
    const int cls = wave*256 + wt*16 + quad*4;
    if (cls < C){
      float4 o0, o1;
      o0.x = fmaf(nscale, (float)dd0[wt][0][0], bias0);
      o0.y = fmaf(nscale, (float)dd0[wt][0][1], bias0);
      o0.z = fmaf(nscale, (float)dd0[wt][1][0], bias0);
      o0.w = fmaf(nscale, (float)dd0[wt][1][1], bias0);
      o1.x = fmaf(nscale, (float)dd1[wt][0][0], bias1);
      o1.y = fmaf(nscale, (float)dd1[wt][0][1], bias1);
      o1.z = fmaf(nscale, (float)dd1[wt][1][0], bias1);
      o1.w = fmaf(nscale, (float)dd1[wt][1][1], bias1);
      *(float4*)(orow0 + cls) = o0;
      *(float4*)(orow1 + cls) = o1;
    }
  }
}

extern "C" void kernel_launch(void* const* d_in, const int* in_sizes, int n_in,
                              void* d_out, int out_size, void* d_ws, size_t ws_size,
                              hipStream_t stream) {
  const float* features = (const float*)d_in[0];
  const float* protos   = (const float*)d_in[1];
  const float* dscale   = (const float*)d_in[2];
  const float* temp     = (const float*)d_in[3];
  float* out = (float*)d_out;

  const int F = 256;
  const int B = in_sizes[0] / F;   // 32768
  const int C = in_sizes[1] / F;   // 1000

  unsigned short* pnw = (unsigned short*)d_ws;   // [1024 x 256] bf16, permuted

  norm_protos_kernel<<<CPAD/4, 256, 0, stream>>>(protos, pnw, C);
  fused_kernel<<<B/32, 256, 0, stream>>>(features, pnw, dscale, temp, out, C);
}